// Round 10
// baseline (235.271 us; speedup 1.0000x reference)
//
#include <hip/hip_runtime.h>
#include <hip/hip_bf16.h>
#include <math.h>

#define BB 2
#define NN 8192
#define DD 512
#define HH 8
#define DK 64
#define KNB 32
#define BN (BB*NN)          // 16384 rows
#define BHN (BB*HH*NN)      // 131072 (b,h,n) tuples

typedef __attribute__((ext_vector_type(8))) _Float16 f16x8;   // 8 f16 in 4 VGPRs
typedef __attribute__((ext_vector_type(2))) _Float16 f16x2;
typedef __attribute__((ext_vector_type(4))) float f32x4;

#if __has_builtin(__builtin_amdgcn_fdot2)
#define HAS_FDOT2 1
#endif

__device__ __forceinline__ unsigned short f2h(float f) {
    return __builtin_bit_cast(unsigned short, (_Float16)f);
}
__device__ __forceinline__ f16x2 u2h2(unsigned u) {
    return __builtin_bit_cast(f16x2, u);
}
__device__ __forceinline__ float h2f_lo(unsigned u) {
    return (float)__builtin_bit_cast(_Float16, (unsigned short)(u & 0xffffu));
}
__device__ __forceinline__ float h2f_hi(unsigned u) {
    return (float)__builtin_bit_cast(_Float16, (unsigned short)(u >> 16));
}
// dot of packed f16 pairs with fp32 accumulate
__device__ __forceinline__ float dot2h(unsigned a, unsigned b, float c) {
#ifdef HAS_FDOT2
    return __builtin_amdgcn_fdot2(u2h2(a), u2h2(b), c, false);
#else
    c = fmaf(h2f_lo(a), h2f_lo(b), c);
    return fmaf(h2f_hi(a), h2f_hi(b), c);
#endif
}

// packed f32x2 -> f16x2 (RTZ) as a raw dword. The builtin returns
// __fp16 ext_vector_type(2) -- bit_cast it immediately (round-9 compile fix).
__device__ __forceinline__ unsigned cvt2h(float lo, float hi) {
    return __builtin_bit_cast(unsigned, __builtin_amdgcn_cvt_pkrtz(lo, hi));
}

// async global->LDS DMA. LDS dest is wave-uniform base; HW adds lane*width.
__device__ __forceinline__ void gload_lds16(const void* gptr, void* lptr) {
    __builtin_amdgcn_global_load_lds(
        (const __attribute__((address_space(1))) unsigned int*)gptr,
        (__attribute__((address_space(3))) unsigned int*)lptr,
        16, 0, 0);
}

// ---------------- fp32 -> f16 converter (weights only; x is fused into gemm_qkv) ----------------
__global__ __launch_bounds__(256) void cvt_w(
    const float* __restrict__ Wq, const float* __restrict__ Wk,
    const float* __restrict__ Wv, const float* __restrict__ Wo,
    unsigned short* __restrict__ Wfb, unsigned short* __restrict__ Wob)
{
    const int e = (blockIdx.x * 256 + threadIdx.x) * 4;   // over 4*262144
    const int t = e >> 18;
    const int off = e & 262143;
    const float* src = (t == 0) ? Wq : (t == 1) ? Wk : (t == 2) ? Wv : Wo;
    unsigned short* dst = (t < 3) ? (Wfb + (size_t)t * 262144) : Wob;
    const float4 v = *(const float4*)(src + off);
    ushort4 u;
    u.x = f2h(v.x); u.y = f2h(v.y); u.z = f2h(v.z); u.w = f2h(v.w);
    *(ushort4*)(dst + off) = u;
}

// ---------------- Kernel 1: fused f32->f16 + QKV projection + LayerNorm ----------------
// A (= x) staged directly from f32 global with in-flight conversion,
// eliminating the cvt_all x-pass (96 MB HBM). Per K-step:
//   top:    issue 4 coalesced float4 loads for A tile t+1 (8x128-B segs/wave)
//           + 2 gload_lds16 for B tile t+1                       [issue early]
//   middle: ds_read + 16 MFMA on tile t (covers the load latency)
//   bottom: cvt_pkrtz + ds_write of A t+1 into the other buffer  [write late]
//   __syncthreads()  (drains B DMA; A writes are plain LDS ops)
// LDS layout (f16 [128][32], 64-B rows), MFMA path, LN, epilogue: unchanged
// from the passing r7 kernel. x quantization is RTZ vs RNE before; error
// budget has 4x margin.
__global__ __launch_bounds__(256) void gemm_qkv(
    const float* __restrict__ x, const unsigned short* __restrict__ Wfb,
    unsigned short* __restrict__ Qh, unsigned short* __restrict__ Kh,
    unsigned short* __restrict__ Vh)
{
    __shared__ unsigned short Als[2][128 * 32];   // 16 KB (f16, converted in-flight)
    __shared__ unsigned short Bls[2][128 * 32];   // 16 KB
    const int tid  = threadIdx.x;
    const int wave = tid >> 6, lane = tid & 63;
    const int wm = wave >> 1, wn = wave & 1;
    const int quad = lane >> 4, r = lane & 15;
    const int p = blockIdx.x;                 // 0..1535
    const int L = (p & 7) * 192 + (p >> 3);   // XCD-contiguous logical id
    const int row0 = (L / 12) * 128;
    const int c0   = (L % 12) * 128;          // 128 | 512 so tile is within one tensor

    f32x4 acc[4][4];
    #pragma unroll
    for (int i = 0; i < 4; ++i)
        #pragma unroll
        for (int j = 0; j < 4; ++j) acc[i][j] = (f32x4)0.f;

    const char* Bb = (const char*)Wfb;

    // B staging geometry (unchanged)
    const int li0 = wave * 1024 + lane * 16;
    const int rr0 = li0 >> 6, off0 = li0 & 63;        // rows 0..63 half
    const int li1 = 4096 + li0;
    const int rr1 = li1 >> 6, off1 = li1 & 63;        // rows 64..127 half

    // A staging geometry: thread covers 4 rows (i*32 + ar), 16 B (4 f32) each
    const int ar = tid >> 3;          // 0..31
    const int aq = tid & 7;           // 8 lanes x 16 B = 128-B segment per row

    float4 va[4];
    // ---- prologue: tile 0 ----
    #pragma unroll
    for (int i = 0; i < 4; ++i)
        va[i] = *(const float4*)(x + (size_t)(row0 + i * 32 + ar) * 512 + aq * 4);
    gload_lds16(Bb + (size_t)(c0 + rr0) * 1024 + off0, (char*)Bls[0] + (wave * 1024));
    gload_lds16(Bb + (size_t)(c0 + rr1) * 1024 + off1, (char*)Bls[0] + (4096 + wave * 1024));
    #pragma unroll
    for (int i = 0; i < 4; ++i) {
        uint2 u;
        u.x = cvt2h(va[i].x, va[i].y);
        u.y = cvt2h(va[i].z, va[i].w);
        *(uint2*)((char*)Als[0] + (i * 32 + ar) * 64 + aq * 8) = u;
    }
    __syncthreads();    // tile 0 resident (B DMA drained by barrier's vmcnt wait)

    for (int kt = 0; kt < 16; ++kt) {
        const int cur = kt & 1;
        if (kt < 15) {   // issue loads for tile kt+1 (A f32 to regs, B via DMA)
            const int ke = (kt + 1) * 32;            // f32-element K offset
            #pragma unroll
            for (int i = 0; i < 4; ++i)
                va[i] = *(const float4*)(x + (size_t)(row0 + i * 32 + ar) * 512 + ke + aq * 4);
            const int kb = (kt + 1) * 64;            // byte K offset (f16)
            gload_lds16(Bb + (size_t)(c0 + rr0) * 1024 + kb + off0, (char*)Bls[cur ^ 1] + (wave * 1024));
            gload_lds16(Bb + (size_t)(c0 + rr1) * 1024 + kb + off1, (char*)Bls[cur ^ 1] + (4096 + wave * 1024));
        }

        f16x8 af[4], bf[4];
        #pragma unroll
        for (int i = 0; i < 4; ++i)
            af[i] = *(const f16x8*)(&Als[cur][(wm * 64 + i * 16 + r) * 32 + quad * 8]);
        #pragma unroll
        for (int j = 0; j < 4; ++j)
            bf[j] = *(const f16x8*)(&Bls[cur][(wn * 64 + j * 16 + r) * 32 + quad * 8]);
        #pragma unroll
        for (int i = 0; i < 4; ++i)
            #pragma unroll
            for (int j = 0; j < 4; ++j)
                acc[i][j] = __builtin_amdgcn_mfma_f32_16x16x32_f16(af[i], bf[j], acc[i][j], 0, 0, 0);

        if (kt < 15) {   // convert + write A tile kt+1 (loads had the MFMA phase to land)
            #pragma unroll
            for (int i = 0; i < 4; ++i) {
                uint2 u;
                u.x = cvt2h(va[i].x, va[i].y);
                u.y = cvt2h(va[i].z, va[i].w);
                *(uint2*)((char*)Als[cur ^ 1] + (i * 32 + ar) * 64 + aq * 8) = u;
            }
        }
        __syncthreads();   // B DMA drained + buffer handoff
    }

    const int tensor = c0 >> 9;   // block-uniform: 0=Q 1=K 2=V
    unsigned short* OutH = (tensor == 0) ? Qh : (tensor == 1) ? Kh : Vh;

    float mu[4][4], rs[4][4];
    if (tensor < 2) {
        #pragma unroll
        for (int i = 0; i < 4; ++i) {
            #pragma unroll
            for (int reg = 0; reg < 4; ++reg) {
                float sm = acc[i][0][reg] + acc[i][1][reg] + acc[i][2][reg] + acc[i][3][reg];
                sm += __shfl_xor(sm, 1); sm += __shfl_xor(sm, 2);
                sm += __shfl_xor(sm, 4); sm += __shfl_xor(sm, 8);
                const float muv = sm * (1.f / 64.f);
                float qv = 0.f;
                #pragma unroll
                for (int j = 0; j < 4; ++j) {
                    const float dv = acc[i][j][reg] - muv;
                    qv = fmaf(dv, dv, qv);
                }
                qv += __shfl_xor(qv, 1); qv += __shfl_xor(qv, 2);
                qv += __shfl_xor(qv, 4); qv += __shfl_xor(qv, 8);
                mu[i][reg] = muv;
                rs[i][reg] = rsqrtf(qv * (1.f / 64.f) + 1e-5f);
            }
        }
    }

    // C/D layout col=lane&15, row=quad*4+reg (verified m89).
    #pragma unroll
    for (int i = 0; i < 4; ++i) {
        #pragma unroll
        for (int j = 0; j < 4; ++j) {
            const int cc = (c0 & 511) + wn * 64 + j * 16 + r;
            const int h = cc >> 6, d = cc & 63;
            #pragma unroll
            for (int reg = 0; reg < 4; ++reg) {
                const int row = row0 + wm * 64 + i * 16 + quad * 4 + reg;
                const int b = row >> 13, n = row & 8191;
                float v = acc[i][j][reg];
                if (tensor < 2) v = (v - mu[i][reg]) * rs[i][reg];
                OutH[(((size_t)(b * HH + h) * NN + n) << 6) + d] = f2h(v);
            }
        }
    }
}

// ---------------- Kernel 2: gather-attention, zero-LDS direct-from-L2 PV ----------------
// Round-6/7 version verbatim (75.0 us, measured 3x). Round-8 lesson: attn is
// MLP-bound -- never reduce the count of concurrent gather loads (16/task).
__global__ __launch_bounds__(256, 2) void attn(
    const unsigned short* __restrict__ Qh, const unsigned short* __restrict__ Kh,
    const unsigned short* __restrict__ Vh,
    const int* __restrict__ idx, unsigned short* __restrict__ Ob)
{
    const int p = blockIdx.x;                       // 0..32767
    const int L = ((p & 7) << 12) | (p >> 3);       // XCD-contiguous logical id
    const int wave = threadIdx.x >> 6;
    const int wid  = L * 4 + wave;                  // 0..BHN-1
    const int lane = threadIdx.x & 63;
    const int bh = wid >> 13;
    const int n  = wid & 8191;
    const size_t base = (size_t)bh * NN * DK;       // element offset of (b,h) slab

    // canonical neighbor layout: lane l holds g_l (l<32; upper half duplicates)
    const int g_all = idx[n * KNB + (lane & 31)];

    // Score. Half-row dot: 32 elements each, as 16 packed f16 pairs, 2 chains.
    const int k    = lane >> 1;
    const int half = lane & 1;
    const int g    = __builtin_amdgcn_ds_bpermute(k * 4, g_all);

    const uint4* q4 = (const uint4*)(Qh + base + ((size_t)n << 6) + half * 32);
    const uint4* k4 = (const uint4*)(Kh + base + ((size_t)g << 6) + half * 32);
    float a0 = 0.f, a1 = 0.f;
    {
        const uint4 qa = q4[0], ka = k4[0];
        a0 = dot2h(qa.x, ka.x, a0); a0 = dot2h(qa.y, ka.y, a0);
        a0 = dot2h(qa.z, ka.z, a0); a0 = dot2h(qa.w, ka.w, a0);
    }
    {
        const uint4 qa = q4[1], ka = k4[1];
        a1 = dot2h(qa.x, ka.x, a1); a1 = dot2h(qa.y, ka.y, a1);
        a1 = dot2h(qa.z, ka.z, a1); a1 = dot2h(qa.w, ka.w, a1);
    }
    {
        const uint4 qa = q4[2], ka = k4[2];
        a0 = dot2h(qa.x, ka.x, a0); a0 = dot2h(qa.y, ka.y, a0);
        a0 = dot2h(qa.z, ka.z, a0); a0 = dot2h(qa.w, ka.w, a0);
    }
    {
        const uint4 qa = q4[3], ka = k4[3];
        a1 = dot2h(qa.x, ka.x, a1); a1 = dot2h(qa.y, ka.y, a1);
        a1 = dot2h(qa.z, ka.z, a1); a1 = dot2h(qa.w, ka.w, a1);
    }
    const float acc = a0 + a1;
    const float s = (acc + __shfl_xor(acc, 1)) * 0.125f;  // 1/sqrt(64)

    // softmax over 32 distinct neighbors (values pair-duplicated); no max
    // subtraction needed: |s| <= ~8.03 (LN'd rows), e^s <= 3.1e3 in f32.
    const float e = __expf(s);
    float tot = e;
    #pragma unroll
    for (int off = 2; off <= 32; off <<= 1) tot += __shfl_xor(tot, off);
    const float pr = e / tot;

    // Pack p pairs (f16): lane 4j holds p_{2j} | p_{2j+1}<<16.
    const unsigned prh = (unsigned)f2h(pr);
    const unsigned pp = prh | (((unsigned)__shfl_xor((int)prh, 2)) << 16);

    // PV, direct from global/L2. Lane owns dims (2c, 2c+1); half h2 handles
    // rows 16*h2 .. 16*h2+15 (8 pairs -> 16 concurrent V loads, keep them).
    const char* Vbytes = (const char*)Vh + (base << 1);
    const int c2 = lane & 31, h2 = lane >> 5;
    float o0 = 0.f, o1 = 0.f;
    #pragma unroll
    for (int j = 0; j < 8; ++j) {
        const int r0 = __builtin_amdgcn_ds_bpermute((h2 * 16 + 2 * j) * 4, g_all);
        const int r1 = __builtin_amdgcn_ds_bpermute((h2 * 16 + 2 * j + 1) * 4, g_all);
        const unsigned vx = *(const unsigned*)(Vbytes + (size_t)(r0 * 128) + c2 * 4); // row 16h2+2j
        const unsigned vy = *(const unsigned*)(Vbytes + (size_t)(r1 * 128) + c2 * 4); // row 16h2+2j+1
        // p pair for rows (16h2+2j, 16h2+2j+1) lives at lane 32h2+4j.
        const unsigned ppj = (unsigned)__builtin_amdgcn_ds_bpermute(h2 * 128 + j * 16, (int)pp);
        const unsigned t0 = __builtin_amdgcn_perm(vx, vy, 0x01000504u); // (vx.lo, vy.lo)
        const unsigned t1 = __builtin_amdgcn_perm(vx, vy, 0x03020706u); // (vx.hi, vy.hi)
        o0 = dot2h(t0, ppj, o0);   // dim 2c
        o1 = dot2h(t1, ppj, o1);   // dim 2c+1
    }
    o0 += __shfl_xor(o0, 32);
    o1 += __shfl_xor(o1, 32);
    if (lane < 32) {
        const int b = bh >> 3, hh = bh & 7;
        const unsigned ov = (unsigned)f2h(o0) | ((unsigned)f2h(o1) << 16);
        *(unsigned*)(Ob + ((size_t)(b * NN + n)) * DD + hh * DK + 2 * c2) = ov;
    }
}

// ---------------- Kernel 3: output projection, f16 MFMA ----------------
// 2-phase + XCD-swizzle (r7, neutral-kept).
__global__ __launch_bounds__(256) void gemm_out(
    const unsigned short* __restrict__ Ob, const unsigned short* __restrict__ Wob,
    const float* __restrict__ bout, float* __restrict__ out)
{
    __shared__ unsigned short Als[2][128 * 32];
    __shared__ unsigned short Bls[2][128 * 32];
    const int tid  = threadIdx.x;
    const int wave = tid >> 6, lane = tid & 63;
    const int wm = wave >> 1, wn = wave & 1;
    const int quad = lane >> 4, r = lane & 15;
    const int p = blockIdx.x;                 // 0..511
    const int L = (p & 7) * 64 + (p >> 3);    // XCD-contiguous logical id
    const int row0 = (L >> 2) * 128;
    const int c0   = (L & 3) * 128;

    f32x4 acc[4][4];
    #pragma unroll
    for (int i = 0; i < 4; ++i)
        #pragma unroll
        for (int j = 0; j < 4; ++j) acc[i][j] = (f32x4)0.f;

    const char* Ab = (const char*)Ob;
    const char* Bb = (const char*)Wob;

    const int li0 = wave * 1024 + lane * 16;
    const int rr0 = li0 >> 6, off0 = li0 & 63;
    const int li1 = 4096 + li0;
    const int rr1 = li1 >> 6, off1 = li1 & 63;

    {
        gload_lds16(Ab + (size_t)(row0 + rr0) * 1024 + off0, (char*)Als[0] + (wave * 1024));
        gload_lds16(Bb + (size_t)(c0   + rr0) * 1024 + off0, (char*)Bls[0] + (wave * 1024));
        gload_lds16(Ab + (size_t)(row0 + rr1) * 1024 + off1, (char*)Als[0] + (4096 + wave * 1024));
        gload_lds16(Bb + (size_t)(c0   + rr1) * 1024 + off1, (char*)Bls[0] + (4096 + wave * 1024));
    }
    __syncthreads();

    for (int kt = 0; kt < 16; ++kt) {
        const int cur = kt & 1;
        if (kt < 15) {
            const int kb = (kt + 1) * 64;
            gload_lds16(Ab + (size_t)(row0 + rr0) * 1024 + kb + off0, (char*)Als[cur ^ 1] + (wave * 1024));
            gload_lds16(Bb + (size_t)(c0   + rr0) * 1024 + kb + off0, (char*)Bls[cur ^ 1] + (wave * 1024));
            gload_lds16(Ab + (size_t)(row0 + rr1) * 1024 + kb + off1, (char*)Als[cur ^ 1] + (4096 + wave * 1024));
            gload_lds16(Bb + (size_t)(c0   + rr1) * 1024 + kb + off1, (char*)Bls[cur ^ 1] + (4096 + wave * 1024));
        }

        f16x8 af[4], bf[4];
        #pragma unroll
        for (int i = 0; i < 4; ++i)
            af[i] = *(const f16x8*)(&Als[cur][(wm * 64 + i * 16 + r) * 32 + quad * 8]);
        #pragma unroll
        for (int j = 0; j < 4; ++j)
            bf[j] = *(const f16x8*)(&Bls[cur][(wn * 64 + j * 16 + r) * 32 + quad * 8]);
        #pragma unroll
        for (int i = 0; i < 4; ++i)
            #pragma unroll
            for (int j = 0; j < 4; ++j)
                acc[i][j] = __builtin_amdgcn_mfma_f32_16x16x32_f16(af[i], bf[j], acc[i][j], 0, 0, 0);

        __syncthreads();
    }

    #pragma unroll
    for (int i = 0; i < 4; ++i) {
        #pragma unroll
        for (int j = 0; j < 4; ++j) {
            const int colg = c0 + wn * 64 + j * 16 + r;
            const float bb = bout[colg];
            #pragma unroll
            for (int reg = 0; reg < 4; ++reg) {
                const int row = row0 + wm * 64 + i * 16 + quad * 4 + reg;
                out[((size_t)row << 9) + colg] = acc[i][j][reg] + bb;
            }
        }
    }
}

extern "C" void kernel_launch(void* const* d_in, const int* in_sizes, int n_in,
                              void* d_out, int out_size, void* d_ws, size_t ws_size,
                              hipStream_t stream)
{
    const float* x    = (const float*)d_in[0];
    const int*   idx  = (const int*)  d_in[1];
    const float* Wq   = (const float*)d_in[2];
    const float* Wk   = (const float*)d_in[3];
    const float* Wv   = (const float*)d_in[4];
    const float* Wout = (const float*)d_in[5];
    const float* bout = (const float*)d_in[6];

    char* ws = (char*)d_ws;
    unsigned short* Qh  = (unsigned short*)(ws);              // 16777216 B
    unsigned short* Kh  = (unsigned short*)(ws + 16777216);   // 16777216 B
    unsigned short* Vh  = (unsigned short*)(ws + 33554432);   // 16777216 B
    unsigned short* Ob  = (unsigned short*)(ws + 50331648);   // 16777216 B
    unsigned short* Wfb = (unsigned short*)(ws + 67108864);   // 1572864 B (Wq|Wk|Wv rows)
    unsigned short* Wob = (unsigned short*)(ws + 68681728);   // 524288 B
    float* out = (float*)d_out;

    cvt_w<<<1024, 256, 0, stream>>>(Wq, Wk, Wv, Wout, Wfb, Wob);   // weights only (~4 MB)

    gemm_qkv<<<1536, 256, 0, stream>>>(x, Wfb, Qh, Kh, Vh);        // x converted in-flight

    attn<<<BHN / 4, 256, 0, stream>>>(Qh, Kh, Vh, idx, Ob);

    gemm_out<<<512, 256, 0, stream>>>(Ob, Wob, bout, out);
}

// Round 11
// 221.021 us; speedup vs baseline: 1.0645x; 1.0645x over previous
//
#include <hip/hip_runtime.h>
#include <hip/hip_bf16.h>
#include <math.h>

#define BB 2
#define NN 8192
#define DD 512
#define HH 8
#define DK 64
#define KNB 32
#define BN (BB*NN)          // 16384 rows
#define BHN (BB*HH*NN)      // 131072 (b,h,n) tuples

typedef __attribute__((ext_vector_type(8))) _Float16 f16x8;   // 8 f16 in 4 VGPRs
typedef __attribute__((ext_vector_type(2))) _Float16 f16x2;
typedef __attribute__((ext_vector_type(4))) float f32x4;

#if __has_builtin(__builtin_amdgcn_fdot2)
#define HAS_FDOT2 1
#endif

__device__ __forceinline__ unsigned short f2h(float f) {
    return __builtin_bit_cast(unsigned short, (_Float16)f);
}
__device__ __forceinline__ f16x2 u2h2(unsigned u) {
    return __builtin_bit_cast(f16x2, u);
}
__device__ __forceinline__ float h2f_lo(unsigned u) {
    return (float)__builtin_bit_cast(_Float16, (unsigned short)(u & 0xffffu));
}
__device__ __forceinline__ float h2f_hi(unsigned u) {
    return (float)__builtin_bit_cast(_Float16, (unsigned short)(u >> 16));
}
// dot of packed f16 pairs with fp32 accumulate
__device__ __forceinline__ float dot2h(unsigned a, unsigned b, float c) {
#ifdef HAS_FDOT2
    return __builtin_amdgcn_fdot2(u2h2(a), u2h2(b), c, false);
#else
    c = fmaf(h2f_lo(a), h2f_lo(b), c);
    return fmaf(h2f_hi(a), h2f_hi(b), c);
#endif
}

// async global->LDS DMA. LDS dest is wave-uniform base; HW adds lane*width.
__device__ __forceinline__ void gload_lds16(const void* gptr, void* lptr) {
    __builtin_amdgcn_global_load_lds(
        (const __attribute__((address_space(1))) unsigned int*)gptr,
        (__attribute__((address_space(3))) unsigned int*)lptr,
        16, 0, 0);
}

// ---------------- fp32 -> f16 converter (x + all weights, one launch) ----------------
__global__ __launch_bounds__(256) void cvt_all(
    const float* __restrict__ x,
    const float* __restrict__ Wq, const float* __restrict__ Wk,
    const float* __restrict__ Wv, const float* __restrict__ Wo,
    unsigned short* __restrict__ Xb, unsigned short* __restrict__ Wfb,
    unsigned short* __restrict__ Wob)
{
    const int blk = blockIdx.x;
    const float* src;
    unsigned short* dst;
    int off;
    if (blk < 8192) {
        off = (blk * 256 + threadIdx.x) * 4;
        src = x; dst = Xb;
    } else {
        const int e = ((blk - 8192) * 256 + threadIdx.x) * 4;   // over 4*262144
        const int t = e >> 18;
        off = e & 262143;
        src = (t == 0) ? Wq : (t == 1) ? Wk : (t == 2) ? Wv : Wo;
        dst = (t < 3) ? (Wfb + (size_t)t * 262144) : Wob;
    }
    const float4 v = *(const float4*)(src + off);
    ushort4 u;
    u.x = f2h(v.x); u.y = f2h(v.y); u.z = f2h(v.z); u.w = f2h(v.w);
    *(ushort4*)(dst + off) = u;
}

// ---------------- Kernel 1: fused QKV projection + LayerNorm, f16 MFMA ----------------
// Round-11 change: T2 LDS XOR-swizzle via pre-swizzled DMA SOURCE (m201-legal:
// linear gload_lds dest + source unit permuted by the same involution) +
// swizzled fragment reads. The old read pattern (byte row*64 + quad*16) was an
// 8-WAY bank conflict: bank = (r&1)*16 + quad*4 + d, independent of the row
// bits varying across lanes -- present in every GEMM variant since round 1
// (r10 counters: SQ_LDS_BANK_CONFLICT = 3.1M). Swizzle: 16B-unit
// q_lds = q_global ^ ((row&6)>>1); read addr byte = row*64 + (quad*16 ^
// ((r&6)<<3)). Involution, both sides consistent. No arithmetic change.
// (Round-10 fused-x path reverted: net -14 us -- cvt saving < qkv regression.)
__global__ __launch_bounds__(256) void gemm_qkv(
    const unsigned short* __restrict__ Xb, const unsigned short* __restrict__ Wfb,
    unsigned short* __restrict__ Qh, unsigned short* __restrict__ Kh,
    unsigned short* __restrict__ Vh)
{
    __shared__ unsigned short Als[2][128 * 32];   // 16 KB
    __shared__ unsigned short Bls[2][128 * 32];   // 16 KB
    const int tid  = threadIdx.x;
    const int wave = tid >> 6, lane = tid & 63;
    const int wm = wave >> 1, wn = wave & 1;
    const int quad = lane >> 4, r = lane & 15;
    const int p = blockIdx.x;                 // 0..1535
    const int L = (p & 7) * 192 + (p >> 3);   // XCD-contiguous logical id
    const int row0 = (L / 12) * 128;
    const int c0   = (L % 12) * 128;          // 128 | 512 so tile is within one tensor

    f32x4 acc[4][4];
    #pragma unroll
    for (int i = 0; i < 4; ++i)
        #pragma unroll
        for (int j = 0; j < 4; ++j) acc[i][j] = (f32x4)0.f;

    const char* Ab = (const char*)Xb;
    const char* Bb = (const char*)Wfb;

    // DMA geometry: lane l covers row wave*16 + (l>>2) (+64 for second half),
    // fetching global 16B-unit (l&3) ^ ((l>>3)&3)  [= (row&6)>>1 pre-swizzle].
    const int rr0  = wave * 16 + (lane >> 2);          // rows 0..63 half
    const int rr1  = 64 + rr0;                         // rows 64..127 half
    const int offS = ((lane & 3) ^ ((lane >> 3) & 3)) << 4;

    // prologue: stage tile 0 into buffer 0
    {
        gload_lds16(Ab + (size_t)(row0 + rr0) * 1024 + offS, (char*)Als[0] + (wave * 1024));
        gload_lds16(Bb + (size_t)(c0   + rr0) * 1024 + offS, (char*)Bls[0] + (wave * 1024));
        gload_lds16(Ab + (size_t)(row0 + rr1) * 1024 + offS, (char*)Als[0] + (4096 + wave * 1024));
        gload_lds16(Bb + (size_t)(c0   + rr1) * 1024 + offS, (char*)Bls[0] + (4096 + wave * 1024));
    }
    __syncthreads();    // drains vmcnt -> tile 0 resident

    const int swz = (r & 6) << 3;                      // read-side XOR (bytes)

    for (int kt = 0; kt < 16; ++kt) {
        const int cur = kt & 1;
        if (kt < 15) {   // stage tile kt+1 into the other buffer
            const int kb = (kt + 1) * 64;   // byte offset of K-slice
            gload_lds16(Ab + (size_t)(row0 + rr0) * 1024 + kb + offS, (char*)Als[cur ^ 1] + (wave * 1024));
            gload_lds16(Bb + (size_t)(c0   + rr0) * 1024 + kb + offS, (char*)Bls[cur ^ 1] + (wave * 1024));
            gload_lds16(Ab + (size_t)(row0 + rr1) * 1024 + kb + offS, (char*)Als[cur ^ 1] + (4096 + wave * 1024));
            gload_lds16(Bb + (size_t)(c0   + rr1) * 1024 + kb + offS, (char*)Bls[cur ^ 1] + (4096 + wave * 1024));
        }

        f16x8 af[4], bf[4];
        #pragma unroll
        for (int i = 0; i < 4; ++i)
            af[i] = *(const f16x8*)((const char*)Als[cur] + (wm * 64 + i * 16 + r) * 64 + (quad * 16 ^ swz));
        #pragma unroll
        for (int j = 0; j < 4; ++j)
            bf[j] = *(const f16x8*)((const char*)Bls[cur] + (wn * 64 + j * 16 + r) * 64 + (quad * 16 ^ swz));
        #pragma unroll
        for (int i = 0; i < 4; ++i)
            #pragma unroll
            for (int j = 0; j < 4; ++j)
                acc[i][j] = __builtin_amdgcn_mfma_f32_16x16x32_f16(af[i], bf[j], acc[i][j], 0, 0, 0);

        __syncthreads();   // staged loads landed (vmcnt drain) + buffer handoff
    }

    const int tensor = c0 >> 9;   // block-uniform: 0=Q 1=K 2=V
    unsigned short* OutH = (tensor == 0) ? Qh : (tensor == 1) ? Kh : Vh;

    float mu[4][4], rs[4][4];
    if (tensor < 2) {
        #pragma unroll
        for (int i = 0; i < 4; ++i) {
            #pragma unroll
            for (int reg = 0; reg < 4; ++reg) {
                float sm = acc[i][0][reg] + acc[i][1][reg] + acc[i][2][reg] + acc[i][3][reg];
                sm += __shfl_xor(sm, 1); sm += __shfl_xor(sm, 2);
                sm += __shfl_xor(sm, 4); sm += __shfl_xor(sm, 8);
                const float muv = sm * (1.f / 64.f);
                float qv = 0.f;
                #pragma unroll
                for (int j = 0; j < 4; ++j) {
                    const float dv = acc[i][j][reg] - muv;
                    qv = fmaf(dv, dv, qv);
                }
                qv += __shfl_xor(qv, 1); qv += __shfl_xor(qv, 2);
                qv += __shfl_xor(qv, 4); qv += __shfl_xor(qv, 8);
                mu[i][reg] = muv;
                rs[i][reg] = rsqrtf(qv * (1.f / 64.f) + 1e-5f);
            }
        }
    }

    // C/D layout col=lane&15, row=quad*4+reg (verified m89).
    #pragma unroll
    for (int i = 0; i < 4; ++i) {
        #pragma unroll
        for (int j = 0; j < 4; ++j) {
            const int cc = (c0 & 511) + wn * 64 + j * 16 + r;
            const int h = cc >> 6, d = cc & 63;
            #pragma unroll
            for (int reg = 0; reg < 4; ++reg) {
                const int row = row0 + wm * 64 + i * 16 + quad * 4 + reg;
                const int b = row >> 13, n = row & 8191;
                float v = acc[i][j][reg];
                if (tensor < 2) v = (v - mu[i][reg]) * rs[i][reg];
                OutH[(((size_t)(b * HH + h) * NN + n) << 6) + d] = f2h(v);
            }
        }
    }
}

// ---------------- Kernel 2: gather-attention, zero-LDS direct-from-L2 PV ----------------
// Round-6/7 version verbatim (75.0 us, measured 3x). Round-8 lesson: attn is
// MLP-bound -- never reduce the count of concurrent gather loads (16/task).
__global__ __launch_bounds__(256, 2) void attn(
    const unsigned short* __restrict__ Qh, const unsigned short* __restrict__ Kh,
    const unsigned short* __restrict__ Vh,
    const int* __restrict__ idx, unsigned short* __restrict__ Ob)
{
    const int p = blockIdx.x;                       // 0..32767
    const int L = ((p & 7) << 12) | (p >> 3);       // XCD-contiguous logical id
    const int wave = threadIdx.x >> 6;
    const int wid  = L * 4 + wave;                  // 0..BHN-1
    const int lane = threadIdx.x & 63;
    const int bh = wid >> 13;
    const int n  = wid & 8191;
    const size_t base = (size_t)bh * NN * DK;       // element offset of (b,h) slab

    // canonical neighbor layout: lane l holds g_l (l<32; upper half duplicates)
    const int g_all = idx[n * KNB + (lane & 31)];

    // Score. Half-row dot: 32 elements each, as 16 packed f16 pairs, 2 chains.
    const int k    = lane >> 1;
    const int half = lane & 1;
    const int g    = __builtin_amdgcn_ds_bpermute(k * 4, g_all);

    const uint4* q4 = (const uint4*)(Qh + base + ((size_t)n << 6) + half * 32);
    const uint4* k4 = (const uint4*)(Kh + base + ((size_t)g << 6) + half * 32);
    float a0 = 0.f, a1 = 0.f;
    {
        const uint4 qa = q4[0], ka = k4[0];
        a0 = dot2h(qa.x, ka.x, a0); a0 = dot2h(qa.y, ka.y, a0);
        a0 = dot2h(qa.z, ka.z, a0); a0 = dot2h(qa.w, ka.w, a0);
    }
    {
        const uint4 qa = q4[1], ka = k4[1];
        a1 = dot2h(qa.x, ka.x, a1); a1 = dot2h(qa.y, ka.y, a1);
        a1 = dot2h(qa.z, ka.z, a1); a1 = dot2h(qa.w, ka.w, a1);
    }
    {
        const uint4 qa = q4[2], ka = k4[2];
        a0 = dot2h(qa.x, ka.x, a0); a0 = dot2h(qa.y, ka.y, a0);
        a0 = dot2h(qa.z, ka.z, a0); a0 = dot2h(qa.w, ka.w, a0);
    }
    {
        const uint4 qa = q4[3], ka = k4[3];
        a1 = dot2h(qa.x, ka.x, a1); a1 = dot2h(qa.y, ka.y, a1);
        a1 = dot2h(qa.z, ka.z, a1); a1 = dot2h(qa.w, ka.w, a1);
    }
    const float acc = a0 + a1;
    const float s = (acc + __shfl_xor(acc, 1)) * 0.125f;  // 1/sqrt(64)

    // softmax over 32 distinct neighbors (values pair-duplicated); no max
    // subtraction needed: |s| <= ~8.03 (LN'd rows), e^s <= 3.1e3 in f32.
    const float e = __expf(s);
    float tot = e;
    #pragma unroll
    for (int off = 2; off <= 32; off <<= 1) tot += __shfl_xor(tot, off);
    const float pr = e / tot;

    // Pack p pairs (f16): lane 4j holds p_{2j} | p_{2j+1}<<16.
    const unsigned prh = (unsigned)f2h(pr);
    const unsigned pp = prh | (((unsigned)__shfl_xor((int)prh, 2)) << 16);

    // PV, direct from global/L2. Lane owns dims (2c, 2c+1); half h2 handles
    // rows 16*h2 .. 16*h2+15 (8 pairs -> 16 concurrent V loads, keep them).
    const char* Vbytes = (const char*)Vh + (base << 1);
    const int c2 = lane & 31, h2 = lane >> 5;
    float o0 = 0.f, o1 = 0.f;
    #pragma unroll
    for (int j = 0; j < 8; ++j) {
        const int r0 = __builtin_amdgcn_ds_bpermute((h2 * 16 + 2 * j) * 4, g_all);
        const int r1 = __builtin_amdgcn_ds_bpermute((h2 * 16 + 2 * j + 1) * 4, g_all);
        const unsigned vx = *(const unsigned*)(Vbytes + (size_t)(r0 * 128) + c2 * 4); // row 16h2+2j
        const unsigned vy = *(const unsigned*)(Vbytes + (size_t)(r1 * 128) + c2 * 4); // row 16h2+2j+1
        // p pair for rows (16h2+2j, 16h2+2j+1) lives at lane 32h2+4j.
        const unsigned ppj = (unsigned)__builtin_amdgcn_ds_bpermute(h2 * 128 + j * 16, (int)pp);
        const unsigned t0 = __builtin_amdgcn_perm(vx, vy, 0x01000504u); // (vx.lo, vy.lo)
        const unsigned t1 = __builtin_amdgcn_perm(vx, vy, 0x03020706u); // (vx.hi, vy.hi)
        o0 = dot2h(t0, ppj, o0);   // dim 2c
        o1 = dot2h(t1, ppj, o1);   // dim 2c+1
    }
    o0 += __shfl_xor(o0, 32);
    o1 += __shfl_xor(o1, 32);
    if (lane < 32) {
        const int b = bh >> 3, hh = bh & 7;
        const unsigned ov = (unsigned)f2h(o0) | ((unsigned)f2h(o1) << 16);
        *(unsigned*)(Ob + ((size_t)(b * NN + n)) * DD + hh * DK + 2 * c2) = ov;
    }
}

// ---------------- Kernel 3: output projection, f16 MFMA ----------------
// Same 2-phase + XCD-swizzle structure; same T2 source-preswizzle + swizzled
// fragment reads as gemm_qkv.
__global__ __launch_bounds__(256) void gemm_out(
    const unsigned short* __restrict__ Ob, const unsigned short* __restrict__ Wob,
    const float* __restrict__ bout, float* __restrict__ out)
{
    __shared__ unsigned short Als[2][128 * 32];
    __shared__ unsigned short Bls[2][128 * 32];
    const int tid  = threadIdx.x;
    const int wave = tid >> 6, lane = tid & 63;
    const int wm = wave >> 1, wn = wave & 1;
    const int quad = lane >> 4, r = lane & 15;
    const int p = blockIdx.x;                 // 0..511
    const int L = (p & 7) * 64 + (p >> 3);    // XCD-contiguous logical id
    const int row0 = (L >> 2) * 128;
    const int c0   = (L & 3) * 128;

    f32x4 acc[4][4];
    #pragma unroll
    for (int i = 0; i < 4; ++i)
        #pragma unroll
        for (int j = 0; j < 4; ++j) acc[i][j] = (f32x4)0.f;

    const char* Ab = (const char*)Ob;
    const char* Bb = (const char*)Wob;

    const int rr0  = wave * 16 + (lane >> 2);
    const int rr1  = 64 + rr0;
    const int offS = ((lane & 3) ^ ((lane >> 3) & 3)) << 4;

    {
        gload_lds16(Ab + (size_t)(row0 + rr0) * 1024 + offS, (char*)Als[0] + (wave * 1024));
        gload_lds16(Bb + (size_t)(c0   + rr0) * 1024 + offS, (char*)Bls[0] + (wave * 1024));
        gload_lds16(Ab + (size_t)(row0 + rr1) * 1024 + offS, (char*)Als[0] + (4096 + wave * 1024));
        gload_lds16(Bb + (size_t)(c0   + rr1) * 1024 + offS, (char*)Bls[0] + (4096 + wave * 1024));
    }
    __syncthreads();

    const int swz = (r & 6) << 3;

    for (int kt = 0; kt < 16; ++kt) {
        const int cur = kt & 1;
        if (kt < 15) {
            const int kb = (kt + 1) * 64;
            gload_lds16(Ab + (size_t)(row0 + rr0) * 1024 + kb + offS, (char*)Als[cur ^ 1] + (wave * 1024));
            gload_lds16(Bb + (size_t)(c0   + rr0) * 1024 + kb + offS, (char*)Bls[cur ^ 1] + (wave * 1024));
            gload_lds16(Ab + (size_t)(row0 + rr1) * 1024 + kb + offS, (char*)Als[cur ^ 1] + (4096 + wave * 1024));
            gload_lds16(Bb + (size_t)(c0   + rr1) * 1024 + kb + offS, (char*)Bls[cur ^ 1] + (4096 + wave * 1024));
        }

        f16x8 af[4], bf[4];
        #pragma unroll
        for (int i = 0; i < 4; ++i)
            af[i] = *(const f16x8*)((const char*)Als[cur] + (wm * 64 + i * 16 + r) * 64 + (quad * 16 ^ swz));
        #pragma unroll
        for (int j = 0; j < 4; ++j)
            bf[j] = *(const f16x8*)((const char*)Bls[cur] + (wn * 64 + j * 16 + r) * 64 + (quad * 16 ^ swz));
        #pragma unroll
        for (int i = 0; i < 4; ++i)
            #pragma unroll
            for (int j = 0; j < 4; ++j)
                acc[i][j] = __builtin_amdgcn_mfma_f32_16x16x32_f16(af[i], bf[j], acc[i][j], 0, 0, 0);

        __syncthreads();
    }

    #pragma unroll
    for (int i = 0; i < 4; ++i) {
        #pragma unroll
        for (int j = 0; j < 4; ++j) {
            const int colg = c0 + wn * 64 + j * 16 + r;
            const float bb = bout[colg];
            #pragma unroll
            for (int reg = 0; reg < 4; ++reg) {
                const int row = row0 + wm * 64 + i * 16 + quad * 4 + reg;
                out[((size_t)row << 9) + colg] = acc[i][j][reg] + bb;
            }
        }
    }
}

extern "C" void kernel_launch(void* const* d_in, const int* in_sizes, int n_in,
                              void* d_out, int out_size, void* d_ws, size_t ws_size,
                              hipStream_t stream)
{
    const float* x    = (const float*)d_in[0];
    const int*   idx  = (const int*)  d_in[1];
    const float* Wq   = (const float*)d_in[2];
    const float* Wk   = (const float*)d_in[3];
    const float* Wv   = (const float*)d_in[4];
    const float* Wout = (const float*)d_in[5];
    const float* bout = (const float*)d_in[6];

    char* ws = (char*)d_ws;
    unsigned short* Qh  = (unsigned short*)(ws);              // 16777216 B
    unsigned short* Kh  = (unsigned short*)(ws + 16777216);   // 16777216 B
    unsigned short* Vh  = (unsigned short*)(ws + 33554432);   // 16777216 B
    unsigned short* Xb  = (unsigned short*)(ws + 50331648);   // 16777216 B; aliased as Ob
    unsigned short* Ob  = Xb;
    unsigned short* Wfb = (unsigned short*)(ws + 67108864);   // 1572864 B (Wq|Wk|Wv rows)
    unsigned short* Wob = (unsigned short*)(ws + 68681728);   // 524288 B
    float* out = (float*)d_out;

    cvt_all<<<9216, 256, 0, stream>>>(x, Wq, Wk, Wv, Wout, Xb, Wfb, Wob);

    gemm_qkv<<<1536, 256, 0, stream>>>(Xb, Wfb, Qh, Kh, Vh);   // 128 row-tiles x 12 col-tiles, XCD-swizzled

    attn<<<BHN / 4, 256, 0, stream>>>(Qh, Kh, Vh, idx, Ob);

    gemm_out<<<512, 256, 0, stream>>>(Ob, Wob, bout, out);     // 128 row-tiles x 4 col-tiles, XCD-swizzled
}

// Round 12
// 220.781 us; speedup vs baseline: 1.0656x; 1.0011x over previous
//
#include <hip/hip_runtime.h>
#include <hip/hip_bf16.h>
#include <math.h>

#define BB 2
#define NN 8192
#define DD 512
#define HH 8
#define DK 64
#define KNB 32
#define BN (BB*NN)          // 16384 rows
#define BHN (BB*HH*NN)      // 131072 (b,h,n) tuples

typedef __attribute__((ext_vector_type(8))) _Float16 f16x8;   // 8 f16 in 4 VGPRs
typedef __attribute__((ext_vector_type(2))) _Float16 f16x2;
typedef __attribute__((ext_vector_type(4))) float f32x4;

#if __has_builtin(__builtin_amdgcn_fdot2)
#define HAS_FDOT2 1
#endif

__device__ __forceinline__ unsigned short f2h(float f) {
    return __builtin_bit_cast(unsigned short, (_Float16)f);
}
__device__ __forceinline__ f16x2 u2h2(unsigned u) {
    return __builtin_bit_cast(f16x2, u);
}
__device__ __forceinline__ float h2f_lo(unsigned u) {
    return (float)__builtin_bit_cast(_Float16, (unsigned short)(u & 0xffffu));
}
__device__ __forceinline__ float h2f_hi(unsigned u) {
    return (float)__builtin_bit_cast(_Float16, (unsigned short)(u >> 16));
}
// dot of packed f16 pairs with fp32 accumulate
__device__ __forceinline__ float dot2h(unsigned a, unsigned b, float c) {
#ifdef HAS_FDOT2
    return __builtin_amdgcn_fdot2(u2h2(a), u2h2(b), c, false);
#else
    c = fmaf(h2f_lo(a), h2f_lo(b), c);
    return fmaf(h2f_hi(a), h2f_hi(b), c);
#endif
}

// async global->LDS DMA. LDS dest is wave-uniform base; HW adds lane*width.
__device__ __forceinline__ void gload_lds16(const void* gptr, void* lptr) {
    __builtin_amdgcn_global_load_lds(
        (const __attribute__((address_space(1))) unsigned int*)gptr,
        (__attribute__((address_space(3))) unsigned int*)lptr,
        16, 0, 0);
}

// ---------------- fp32 -> f16 converter (x + all weights, one launch) ----------------
__global__ __launch_bounds__(256) void cvt_all(
    const float* __restrict__ x,
    const float* __restrict__ Wq, const float* __restrict__ Wk,
    const float* __restrict__ Wv, const float* __restrict__ Wo,
    unsigned short* __restrict__ Xb, unsigned short* __restrict__ Wfb,
    unsigned short* __restrict__ Wob)
{
    const int blk = blockIdx.x;
    const float* src;
    unsigned short* dst;
    int off;
    if (blk < 8192) {
        off = (blk * 256 + threadIdx.x) * 4;
        src = x; dst = Xb;
    } else {
        const int e = ((blk - 8192) * 256 + threadIdx.x) * 4;   // over 4*262144
        const int t = e >> 18;
        off = e & 262143;
        src = (t == 0) ? Wq : (t == 1) ? Wk : (t == 2) ? Wv : Wo;
        dst = (t < 3) ? (Wfb + (size_t)t * 262144) : Wob;
    }
    const float4 v = *(const float4*)(src + off);
    ushort4 u;
    u.x = f2h(v.x); u.y = f2h(v.y); u.z = f2h(v.z); u.w = f2h(v.w);
    *(ushort4*)(dst + off) = u;
}

// ---------------- Kernel 1: fused QKV projection + LayerNorm, f16 MFMA ----------------
// r11 version verbatim: 2-phase dbuf + XCD swizzle + T2 source-preswizzle.
// (T2 at 2-phase measured neutral -- kept: free and correct.)
__global__ __launch_bounds__(256) void gemm_qkv(
    const unsigned short* __restrict__ Xb, const unsigned short* __restrict__ Wfb,
    unsigned short* __restrict__ Qh, unsigned short* __restrict__ Kh,
    unsigned short* __restrict__ Vh)
{
    __shared__ unsigned short Als[2][128 * 32];   // 16 KB
    __shared__ unsigned short Bls[2][128 * 32];   // 16 KB
    const int tid  = threadIdx.x;
    const int wave = tid >> 6, lane = tid & 63;
    const int wm = wave >> 1, wn = wave & 1;
    const int quad = lane >> 4, r = lane & 15;
    const int p = blockIdx.x;                 // 0..1535
    const int L = (p & 7) * 192 + (p >> 3);   // XCD-contiguous logical id
    const int row0 = (L / 12) * 128;
    const int c0   = (L % 12) * 128;          // 128 | 512 so tile is within one tensor

    f32x4 acc[4][4];
    #pragma unroll
    for (int i = 0; i < 4; ++i)
        #pragma unroll
        for (int j = 0; j < 4; ++j) acc[i][j] = (f32x4)0.f;

    const char* Ab = (const char*)Xb;
    const char* Bb = (const char*)Wfb;

    const int rr0  = wave * 16 + (lane >> 2);          // rows 0..63 half
    const int rr1  = 64 + rr0;                         // rows 64..127 half
    const int offS = ((lane & 3) ^ ((lane >> 3) & 3)) << 4;

    {
        gload_lds16(Ab + (size_t)(row0 + rr0) * 1024 + offS, (char*)Als[0] + (wave * 1024));
        gload_lds16(Bb + (size_t)(c0   + rr0) * 1024 + offS, (char*)Bls[0] + (wave * 1024));
        gload_lds16(Ab + (size_t)(row0 + rr1) * 1024 + offS, (char*)Als[0] + (4096 + wave * 1024));
        gload_lds16(Bb + (size_t)(c0   + rr1) * 1024 + offS, (char*)Bls[0] + (4096 + wave * 1024));
    }
    __syncthreads();    // drains vmcnt -> tile 0 resident

    const int swz = (r & 6) << 3;                      // read-side XOR (bytes)

    for (int kt = 0; kt < 16; ++kt) {
        const int cur = kt & 1;
        if (kt < 15) {   // stage tile kt+1 into the other buffer
            const int kb = (kt + 1) * 64;   // byte offset of K-slice
            gload_lds16(Ab + (size_t)(row0 + rr0) * 1024 + kb + offS, (char*)Als[cur ^ 1] + (wave * 1024));
            gload_lds16(Bb + (size_t)(c0   + rr0) * 1024 + kb + offS, (char*)Bls[cur ^ 1] + (wave * 1024));
            gload_lds16(Ab + (size_t)(row0 + rr1) * 1024 + kb + offS, (char*)Als[cur ^ 1] + (4096 + wave * 1024));
            gload_lds16(Bb + (size_t)(c0   + rr1) * 1024 + kb + offS, (char*)Bls[cur ^ 1] + (4096 + wave * 1024));
        }

        f16x8 af[4], bf[4];
        #pragma unroll
        for (int i = 0; i < 4; ++i)
            af[i] = *(const f16x8*)((const char*)Als[cur] + (wm * 64 + i * 16 + r) * 64 + (quad * 16 ^ swz));
        #pragma unroll
        for (int j = 0; j < 4; ++j)
            bf[j] = *(const f16x8*)((const char*)Bls[cur] + (wn * 64 + j * 16 + r) * 64 + (quad * 16 ^ swz));
        #pragma unroll
        for (int i = 0; i < 4; ++i)
            #pragma unroll
            for (int j = 0; j < 4; ++j)
                acc[i][j] = __builtin_amdgcn_mfma_f32_16x16x32_f16(af[i], bf[j], acc[i][j], 0, 0, 0);

        __syncthreads();   // staged loads landed (vmcnt drain) + buffer handoff
    }

    const int tensor = c0 >> 9;   // block-uniform: 0=Q 1=K 2=V
    unsigned short* OutH = (tensor == 0) ? Qh : (tensor == 1) ? Kh : Vh;

    float mu[4][4], rs[4][4];
    if (tensor < 2) {
        #pragma unroll
        for (int i = 0; i < 4; ++i) {
            #pragma unroll
            for (int reg = 0; reg < 4; ++reg) {
                float sm = acc[i][0][reg] + acc[i][1][reg] + acc[i][2][reg] + acc[i][3][reg];
                sm += __shfl_xor(sm, 1); sm += __shfl_xor(sm, 2);
                sm += __shfl_xor(sm, 4); sm += __shfl_xor(sm, 8);
                const float muv = sm * (1.f / 64.f);
                float qv = 0.f;
                #pragma unroll
                for (int j = 0; j < 4; ++j) {
                    const float dv = acc[i][j][reg] - muv;
                    qv = fmaf(dv, dv, qv);
                }
                qv += __shfl_xor(qv, 1); qv += __shfl_xor(qv, 2);
                qv += __shfl_xor(qv, 4); qv += __shfl_xor(qv, 8);
                mu[i][reg] = muv;
                rs[i][reg] = rsqrtf(qv * (1.f / 64.f) + 1e-5f);
            }
        }
    }

    // C/D layout col=lane&15, row=quad*4+reg (verified m89).
    #pragma unroll
    for (int i = 0; i < 4; ++i) {
        #pragma unroll
        for (int j = 0; j < 4; ++j) {
            const int cc = (c0 & 511) + wn * 64 + j * 16 + r;
            const int h = cc >> 6, d = cc & 63;
            #pragma unroll
            for (int reg = 0; reg < 4; ++reg) {
                const int row = row0 + wm * 64 + i * 16 + quad * 4 + reg;
                const int b = row >> 13, n = row & 8191;
                float v = acc[i][j][reg];
                if (tensor < 2) v = (v - mu[i][reg]) * rs[i][reg];
                OutH[(((size_t)(b * HH + h) * NN + n) << 6) + d] = f2h(v);
            }
        }
    }
}

// ---------------- Kernel 2: gather-attention, 1024-thread blocks ----------------
// Round-12 change (ONLY change this round): same per-wave code as the r6/r11
// version (75-76 us, measured 5x), but 16 waves per block instead of 4.
// Theory: attn is MLP-bound (r8) and occupancy sits at 64-67% with zero
// LDS / 36 VGPR -- nothing architectural caps it. 32768 short-lived 4-wave
// blocks plausibly hit the CP dispatch-rate wall. 1024-thread blocks: 8192
// dispatches (4x fewer); 2 resident blocks/CU = full 32 waves.
// Mapping: p in [0,8192): L = ((p&7)<<10)|(p>>3); wid = L*16 + wave
// (bijective over 0..131071; 16 consecutive n per block, same bh -> L2-local).
// No barriers, no LDS, shfl is width-64 (per-wave) -- block size independent.
__global__ __launch_bounds__(1024) void attn(
    const unsigned short* __restrict__ Qh, const unsigned short* __restrict__ Kh,
    const unsigned short* __restrict__ Vh,
    const int* __restrict__ idx, unsigned short* __restrict__ Ob)
{
    const int p = blockIdx.x;                       // 0..8191
    const int L = ((p & 7) << 10) | (p >> 3);       // XCD-contiguous logical id
    const int wave = threadIdx.x >> 6;              // 0..15
    const int wid  = L * 16 + wave;                 // 0..BHN-1
    const int lane = threadIdx.x & 63;
    const int bh = wid >> 13;
    const int n  = wid & 8191;
    const size_t base = (size_t)bh * NN * DK;       // element offset of (b,h) slab

    // canonical neighbor layout: lane l holds g_l (l<32; upper half duplicates)
    const int g_all = idx[n * KNB + (lane & 31)];

    // Score. Half-row dot: 32 elements each, as 16 packed f16 pairs, 2 chains.
    const int k    = lane >> 1;
    const int half = lane & 1;
    const int g    = __builtin_amdgcn_ds_bpermute(k * 4, g_all);

    const uint4* q4 = (const uint4*)(Qh + base + ((size_t)n << 6) + half * 32);
    const uint4* k4 = (const uint4*)(Kh + base + ((size_t)g << 6) + half * 32);
    float a0 = 0.f, a1 = 0.f;
    {
        const uint4 qa = q4[0], ka = k4[0];
        a0 = dot2h(qa.x, ka.x, a0); a0 = dot2h(qa.y, ka.y, a0);
        a0 = dot2h(qa.z, ka.z, a0); a0 = dot2h(qa.w, ka.w, a0);
    }
    {
        const uint4 qa = q4[1], ka = k4[1];
        a1 = dot2h(qa.x, ka.x, a1); a1 = dot2h(qa.y, ka.y, a1);
        a1 = dot2h(qa.z, ka.z, a1); a1 = dot2h(qa.w, ka.w, a1);
    }
    {
        const uint4 qa = q4[2], ka = k4[2];
        a0 = dot2h(qa.x, ka.x, a0); a0 = dot2h(qa.y, ka.y, a0);
        a0 = dot2h(qa.z, ka.z, a0); a0 = dot2h(qa.w, ka.w, a0);
    }
    {
        const uint4 qa = q4[3], ka = k4[3];
        a1 = dot2h(qa.x, ka.x, a1); a1 = dot2h(qa.y, ka.y, a1);
        a1 = dot2h(qa.z, ka.z, a1); a1 = dot2h(qa.w, ka.w, a1);
    }
    const float acc = a0 + a1;
    const float s = (acc + __shfl_xor(acc, 1)) * 0.125f;  // 1/sqrt(64)

    // softmax over 32 distinct neighbors (values pair-duplicated); no max
    // subtraction needed: |s| <= ~8.03 (LN'd rows), e^s <= 3.1e3 in f32.
    const float e = __expf(s);
    float tot = e;
    #pragma unroll
    for (int off = 2; off <= 32; off <<= 1) tot += __shfl_xor(tot, off);
    const float pr = e / tot;

    // Pack p pairs (f16): lane 4j holds p_{2j} | p_{2j+1}<<16.
    const unsigned prh = (unsigned)f2h(pr);
    const unsigned pp = prh | (((unsigned)__shfl_xor((int)prh, 2)) << 16);

    // PV, direct from global/L2. Lane owns dims (2c, 2c+1); half h2 handles
    // rows 16*h2 .. 16*h2+15 (8 pairs -> 16 concurrent V loads, keep them --
    // r8 lesson: never reduce the count of concurrent gather loads).
    const char* Vbytes = (const char*)Vh + (base << 1);
    const int c2 = lane & 31, h2 = lane >> 5;
    float o0 = 0.f, o1 = 0.f;
    #pragma unroll
    for (int j = 0; j < 8; ++j) {
        const int r0 = __builtin_amdgcn_ds_bpermute((h2 * 16 + 2 * j) * 4, g_all);
        const int r1 = __builtin_amdgcn_ds_bpermute((h2 * 16 + 2 * j + 1) * 4, g_all);
        const unsigned vx = *(const unsigned*)(Vbytes + (size_t)(r0 * 128) + c2 * 4); // row 16h2+2j
        const unsigned vy = *(const unsigned*)(Vbytes + (size_t)(r1 * 128) + c2 * 4); // row 16h2+2j+1
        // p pair for rows (16h2+2j, 16h2+2j+1) lives at lane 32h2+4j.
        const unsigned ppj = (unsigned)__builtin_amdgcn_ds_bpermute(h2 * 128 + j * 16, (int)pp);
        const unsigned t0 = __builtin_amdgcn_perm(vx, vy, 0x01000504u); // (vx.lo, vy.lo)
        const unsigned t1 = __builtin_amdgcn_perm(vx, vy, 0x03020706u); // (vx.hi, vy.hi)
        o0 = dot2h(t0, ppj, o0);   // dim 2c
        o1 = dot2h(t1, ppj, o1);   // dim 2c+1
    }
    o0 += __shfl_xor(o0, 32);
    o1 += __shfl_xor(o1, 32);
    if (lane < 32) {
        const int b = bh >> 3, hh = bh & 7;
        const unsigned ov = (unsigned)f2h(o0) | ((unsigned)f2h(o1) << 16);
        *(unsigned*)(Ob + ((size_t)(b * NN + n)) * DD + hh * DK + 2 * c2) = ov;
    }
}

// ---------------- Kernel 3: output projection, f16 MFMA ----------------
// r11 version verbatim (2-phase + XCD swizzle + T2 preswizzle).
__global__ __launch_bounds__(256) void gemm_out(
    const unsigned short* __restrict__ Ob, const unsigned short* __restrict__ Wob,
    const float* __restrict__ bout, float* __restrict__ out)
{
    __shared__ unsigned short Als[2][128 * 32];
    __shared__ unsigned short Bls[2][128 * 32];
    const int tid  = threadIdx.x;
    const int wave = tid >> 6, lane = tid & 63;
    const int wm = wave >> 1, wn = wave & 1;
    const int quad = lane >> 4, r = lane & 15;
    const int p = blockIdx.x;                 // 0..511
    const int L = (p & 7) * 64 + (p >> 3);    // XCD-contiguous logical id
    const int row0 = (L >> 2) * 128;
    const int c0   = (L & 3) * 128;

    f32x4 acc[4][4];
    #pragma unroll
    for (int i = 0; i < 4; ++i)
        #pragma unroll
        for (int j = 0; j < 4; ++j) acc[i][j] = (f32x4)0.f;

    const char* Ab = (const char*)Ob;
    const char* Bb = (const char*)Wob;

    const int rr0  = wave * 16 + (lane >> 2);
    const int rr1  = 64 + rr0;
    const int offS = ((lane & 3) ^ ((lane >> 3) & 3)) << 4;

    {
        gload_lds16(Ab + (size_t)(row0 + rr0) * 1024 + offS, (char*)Als[0] + (wave * 1024));
        gload_lds16(Bb + (size_t)(c0   + rr0) * 1024 + offS, (char*)Bls[0] + (wave * 1024));
        gload_lds16(Ab + (size_t)(row0 + rr1) * 1024 + offS, (char*)Als[0] + (4096 + wave * 1024));
        gload_lds16(Bb + (size_t)(c0   + rr1) * 1024 + offS, (char*)Bls[0] + (4096 + wave * 1024));
    }
    __syncthreads();

    const int swz = (r & 6) << 3;

    for (int kt = 0; kt < 16; ++kt) {
        const int cur = kt & 1;
        if (kt < 15) {
            const int kb = (kt + 1) * 64;
            gload_lds16(Ab + (size_t)(row0 + rr0) * 1024 + kb + offS, (char*)Als[cur ^ 1] + (wave * 1024));
            gload_lds16(Bb + (size_t)(c0   + rr0) * 1024 + kb + offS, (char*)Bls[cur ^ 1] + (wave * 1024));
            gload_lds16(Ab + (size_t)(row0 + rr1) * 1024 + kb + offS, (char*)Als[cur ^ 1] + (4096 + wave * 1024));
            gload_lds16(Bb + (size_t)(c0   + rr1) * 1024 + kb + offS, (char*)Bls[cur ^ 1] + (4096 + wave * 1024));
        }

        f16x8 af[4], bf[4];
        #pragma unroll
        for (int i = 0; i < 4; ++i)
            af[i] = *(const f16x8*)((const char*)Als[cur] + (wm * 64 + i * 16 + r) * 64 + (quad * 16 ^ swz));
        #pragma unroll
        for (int j = 0; j < 4; ++j)
            bf[j] = *(const f16x8*)((const char*)Bls[cur] + (wn * 64 + j * 16 + r) * 64 + (quad * 16 ^ swz));
        #pragma unroll
        for (int i = 0; i < 4; ++i)
            #pragma unroll
            for (int j = 0; j < 4; ++j)
                acc[i][j] = __builtin_amdgcn_mfma_f32_16x16x32_f16(af[i], bf[j], acc[i][j], 0, 0, 0);

        __syncthreads();
    }

    #pragma unroll
    for (int i = 0; i < 4; ++i) {
        #pragma unroll
        for (int j = 0; j < 4; ++j) {
            const int colg = c0 + wn * 64 + j * 16 + r;
            const float bb = bout[colg];
            #pragma unroll
            for (int reg = 0; reg < 4; ++reg) {
                const int row = row0 + wm * 64 + i * 16 + quad * 4 + reg;
                out[((size_t)row << 9) + colg] = acc[i][j][reg] + bb;
            }
        }
    }
}

extern "C" void kernel_launch(void* const* d_in, const int* in_sizes, int n_in,
                              void* d_out, int out_size, void* d_ws, size_t ws_size,
                              hipStream_t stream)
{
    const float* x    = (const float*)d_in[0];
    const int*   idx  = (const int*)  d_in[1];
    const float* Wq   = (const float*)d_in[2];
    const float* Wk   = (const float*)d_in[3];
    const float* Wv   = (const float*)d_in[4];
    const float* Wout = (const float*)d_in[5];
    const float* bout = (const float*)d_in[6];

    char* ws = (char*)d_ws;
    unsigned short* Qh  = (unsigned short*)(ws);              // 16777216 B
    unsigned short* Kh  = (unsigned short*)(ws + 16777216);   // 16777216 B
    unsigned short* Vh  = (unsigned short*)(ws + 33554432);   // 16777216 B
    unsigned short* Xb  = (unsigned short*)(ws + 50331648);   // 16777216 B; aliased as Ob
    unsigned short* Ob  = Xb;
    unsigned short* Wfb = (unsigned short*)(ws + 67108864);   // 1572864 B (Wq|Wk|Wv rows)
    unsigned short* Wob = (unsigned short*)(ws + 68681728);   // 524288 B
    float* out = (float*)d_out;

    cvt_all<<<9216, 256, 0, stream>>>(x, Wq, Wk, Wv, Wout, Xb, Wfb, Wob);

    gemm_qkv<<<1536, 256, 0, stream>>>(Xb, Wfb, Qh, Kh, Vh);   // 128 row-tiles x 12 col-tiles, XCD-swizzled

    attn<<<BHN / 16, 1024, 0, stream>>>(Qh, Kh, Vh, idx, Ob);  // 8192 blocks x 16 waves

    dim3 g2(BN / 128, 512 / 128);
    gemm_out<<<512, 256, 0, stream>>>(Ob, Wob, bout, out);     // 128 row-tiles x 4 col-tiles, XCD-swizzled
}